// Round 13
// baseline (9476.003 us; speedup 1.0000x reference)
//
#include <hip/hip_runtime.h>
#include <stdint.h>

#define BB 512
#define TT 512
#define FF 128
#define UU 256

typedef float f32x4 __attribute__((ext_vector_type(4)));
typedef short short8 __attribute__((ext_vector_type(8)));
typedef int int4v __attribute__((ext_vector_type(4)));
typedef float float4v __attribute__((ext_vector_type(4)));
typedef unsigned short ushort4v __attribute__((ext_vector_type(4)));

__device__ __forceinline__ unsigned short f2bf(float f) {
  union { float f; uint32_t u; } v; v.f = f;
  uint32_t u = v.u;
  u += 0x7fffu + ((u >> 16) & 1u);
  return (unsigned short)(u >> 16);
}
__device__ __forceinline__ float fast_rcp(float x) { return __builtin_amdgcn_rcpf(x); }
__device__ __forceinline__ float sigmoidf_(float x) { return fast_rcp(1.f + __expf(-x)); }
__device__ __forceinline__ float tanhf_(float x) { return 1.f - 2.f * fast_rcp(1.f + __expf(2.f * x)); }

// ---- prep: W^T combined [1024 cols][384 k] bf16, Wo^T [32][256] bf16, zero xch ---------
__global__ void prep_w(const float* __restrict__ Wx, const float* __restrict__ Wh,
                       const float* __restrict__ Wo,
                       unsigned short* __restrict__ Wt, unsigned short* __restrict__ Wot,
                       int* __restrict__ xch) {
  int bidx = blockIdx.x;
  int tid = threadIdx.x; // 384
  if (bidx < 1024) {
    int n = bidx, k = tid;
    float v = (k < FF) ? Wx[(size_t)k * 1024 + n] : Wh[(size_t)(k - FF) * 1024 + n];
    Wt[(size_t)n * 384 + k] = f2bf(v);
  } else if (bidx == 1024) {
    for (int i = tid; i < 32 * 256; i += 384) {
      int o = i >> 8, u = i & 255;
      Wot[o * 256 + u] = f2bf(Wo[(size_t)u * 32 + o]);
    }
  } else {
    // zero 1MB tagged-exchange buffer every launch (plain stores; r10-proven visible to sc0sc1 readers)
    int base = (bidx - 1025) * 2048;  // 128 blocks x 2048 dwords
    for (int i = tid; i < 2048; i += 384) xch[base + i] = 0;
  }
}

// ---- x f32 -> bf16 ----------------------------------------------------------------------
__global__ void conv_x(const float* __restrict__ xf, unsigned short* __restrict__ xb) {
  size_t i = (size_t)blockIdx.x * 1024 + (size_t)threadIdx.x * 4;
  float4v v = *(const float4v*)(xf + i);
  ushort4v o;
  o.x = f2bf(v.x); o.y = f2bf(v.y); o.z = f2bf(v.z); o.w = f2bf(v.w);
  *(ushort4v*)(xb + i) = o;
}

__device__ __forceinline__ short8 load_xfrag(const unsigned short* p) {
  return *(const short8*)p;
}
__device__ __forceinline__ short8 load_xfrag(const float* p) {
  float4v lo = *(const float4v*)p;
  float4v hi = *(const float4v*)(p + 4);
  union { short8 v; unsigned short s[8]; } a;
  a.s[0] = f2bf(lo.x); a.s[1] = f2bf(lo.y); a.s[2] = f2bf(lo.z); a.s[3] = f2bf(lo.w);
  a.s[4] = f2bf(hi.x); a.s[5] = f2bf(hi.y); a.s[6] = f2bf(hi.z); a.s[7] = f2bf(hi.w);
  return a.v;
}

__device__ __forceinline__ void store_sc01(int* p, int v) {
  asm volatile("global_store_dword %0, %1, off sc0 sc1" :: "v"(p), "v"(v) : "memory");
}
__device__ __forceinline__ uint32_t pk2(int lo, int hi) {
  return ((uint32_t)lo >> 16) | ((uint32_t)hi & 0xffff0000u);
}
__device__ __forceinline__ short8 pack2(const int4v& a, const int4v& b) {
  int4v k;
  k.x = (int)pk2(a.x, a.y); k.y = (int)pk2(a.z, a.w);
  k.z = (int)pk2(b.x, b.y); k.w = (int)pk2(b.z, b.w);
  return __builtin_bit_cast(short8, k);
}
__device__ __forceinline__ int tchk(const int4v& v, int t) {
  return ((v.x ^ t) | (v.y ^ t) | (v.z ^ t) | (v.w ^ t)) & 0xffff;
}

__device__ __forceinline__ void load8x4(const int* pb, int4v& a0, int4v& a1, int4v& a2,
                                        int4v& a3, int4v& a4, int4v& a5, int4v& a6, int4v& a7) {
  asm volatile(
      "global_load_dwordx4 %0, %8, off sc0 sc1\n\t"
      "global_load_dwordx4 %1, %8, off offset:16 sc0 sc1\n\t"
      "global_load_dwordx4 %2, %8, off offset:128 sc0 sc1\n\t"
      "global_load_dwordx4 %3, %8, off offset:144 sc0 sc1\n\t"
      "global_load_dwordx4 %4, %8, off offset:256 sc0 sc1\n\t"
      "global_load_dwordx4 %5, %8, off offset:272 sc0 sc1\n\t"
      "global_load_dwordx4 %6, %8, off offset:384 sc0 sc1\n\t"
      "global_load_dwordx4 %7, %8, off offset:400 sc0 sc1\n\t"
      "s_waitcnt vmcnt(0)"
      : "=&v"(a0), "=&v"(a1), "=&v"(a2), "=&v"(a3),
        "=&v"(a4), "=&v"(a5), "=&v"(a6), "=&v"(a7)
      : "v"(pb) : "memory");
}

// poll partner tile: 4 A-frags delivered directly (32 tagged dwords / lane).
// retry path spins on a 16B canary so misses cost r10-prices, not 128B re-reads.
__device__ __forceinline__ void poll_hq(const int* pb, int t, short8* hq) {
  int4v a0, a1, a2, a3, a4, a5, a6, a7;
  for (;;) {
    load8x4(pb, a0, a1, a2, a3, a4, a5, a6, a7);
    int m = tchk(a0, t) | tchk(a1, t) | tchk(a2, t) | tchk(a3, t)
          | tchk(a4, t) | tchk(a5, t) | tchk(a6, t) | tchk(a7, t);
    if (__all(m == 0)) break;
    int4v c;
    do {
      asm volatile("global_load_dwordx4 %0, %1, off sc0 sc1\n\ts_waitcnt vmcnt(0)"
                   : "=&v"(c) : "v"(pb) : "memory");
    } while (!__all(tchk(c, t) == 0));
  }
  __builtin_amdgcn_sched_barrier(0);  // rule #18
  hq[0] = pack2(a0, a1); hq[1] = pack2(a2, a3);
  hq[2] = pack2(a4, a5); hq[3] = pack2(a6, a7);
}

// ---- one tile-phase of one step ----------------------------------------------------------
// xch tile (mt, side, slot): [16 rows][128 units] tagged dwords; base=((mt*2+side)*2+slot)*2048
template <int HALF, typename XT>
__device__ __forceinline__ void step_phase(
    int t, int mt, int tileSel, const XT* __restrict__ x,
    const unsigned short* __restrict__ Wot, float bob, float* __restrict__ out,
    int* __restrict__ xch, const char* ldsWx, char* hdbuf,
    const short8 (&Bh)[4][8], const float (&bias)[4],
    float (&cst)[4], short8 (&xa)[4],
    int w, int l, int lr, int lhi) {
  const int cur = t & 1, nxt = cur ^ 1;
  const int b0 = mt * 16;

  f32x4 acc[4];
#pragma unroll
  for (int g = 0; g < 4; ++g) { f32x4 a4 = {bias[g], bias[g], bias[g], bias[g]}; acc[g] = a4; }

  short8 ho[4], hq[4];
  if (t > 0) {
    // own-half h(t) from this tile's LDS dbuf
#pragma unroll
    for (int ko = 0; ko < 4; ++ko) {
      const int byte = cur * 4096 + lr * 256 + ((ko * 64 + lhi * 16) ^ ((lr & 7) << 4));
      ho[ko] = *(const short8*)(hdbuf + byte);
    }
#pragma unroll
    for (int ko = 0; ko < 4; ++ko)
#pragma unroll
      for (int g = 0; g < 4; ++g)
        acc[g] = __builtin_amdgcn_mfma_f32_16x16x32_bf16(ho[ko], Bh[g][HALF * 4 + ko], acc[g], 0, 0, 0);
  }

  // x-part: B-frags streamed from LDS Wx
#pragma unroll
  for (int kk = 0; kk < 4; ++kk) {
    short8 bx[4];
#pragma unroll
    for (int g = 0; g < 4; ++g)
      bx[g] = *(const short8*)(ldsWx + ((size_t)((w * 16 + g * 4 + kk) * 64 + l)) * 16);
#pragma unroll
    for (int g = 0; g < 4; ++g)
      acc[g] = __builtin_amdgcn_mfma_f32_16x16x32_bf16(xa[kk], bx[g], acc[g], 0, 0, 0);
  }

  // x prefetch for t+1 (issue before the poll)
  {
    const int tn = (t + 1 < TT) ? t + 1 : t;
    const XT* xp = x + ((size_t)(b0 + lr) * TT + tn) * FF + 8 * lhi;
#pragma unroll
    for (int kk = 0; kk < 4; ++kk) xa[kk] = load_xfrag(xp + kk * 32);
  }

  if (t > 0) {
    // partner half: direct A-frag tagged poll
    const int* pb = xch + ((mt * 2 + (1 - HALF)) * 2 + cur) * 2048 + lr * 128 + 8 * lhi;
    poll_hq(pb, t, hq);
#pragma unroll
    for (int ko = 0; ko < 4; ++ko)
#pragma unroll
      for (int g = 0; g < 4; ++g)
        acc[g] = __builtin_amdgcn_mfma_f32_16x16x32_bf16(hq[ko], Bh[g][(1 - HALF) * 4 + ko], acc[g], 0, 0, 0);

    // fused y(t-1) = h(t)·Wo + bo for this block's 16 out-cols, one wave per tile
    if (w == tileSel) {
      f32x4 yacc = {bob, bob, bob, bob};
#pragma unroll
      for (int ko = 0; ko < 4; ++ko) {
        short8 wf = *(const short8*)(Wot + (size_t)(HALF * 16 + lr) * 256 + (HALF * 4 + ko) * 32 + 8 * lhi);
        yacc = __builtin_amdgcn_mfma_f32_16x16x32_bf16(ho[ko], wf, yacc, 0, 0, 0);
      }
#pragma unroll
      for (int ko = 0; ko < 4; ++ko) {
        short8 wf = *(const short8*)(Wot + (size_t)(HALF * 16 + lr) * 256 + ((1 - HALF) * 4 + ko) * 32 + 8 * lhi);
        yacc = __builtin_amdgcn_mfma_f32_16x16x32_bf16(hq[ko], wf, yacc, 0, 0, 0);
      }
#pragma unroll
      for (int r = 0; r < 4; ++r)
        out[((size_t)(b0 + 4 * lhi + r) * TT + (t - 1)) * 32 + HALF * 16 + lr] = yacc[r];
    }
  }

  // gates
  unsigned short hs[4];
#pragma unroll
  for (int r = 0; r < 4; ++r) {
    float zi = acc[0][r], zf = acc[1][r], zg = acc[2][r], zo = acc[3][r];
    float si = sigmoidf_(zi), sf = sigmoidf_(zf), so = sigmoidf_(zo);
    float tg = tanhf_(zg);
    float cn = sf * cst[r] + si * tg;
    cst[r] = cn;
    hs[r] = f2bf(so * tanhf_(cn));
  }

  // publish h(t+1): own LDS dbuf + tagged xch dwords (fire-and-forget)
  const int wb = ((mt * 2 + HALF) * 2 + nxt) * 2048 + w * 16 + lr;
#pragma unroll
  for (int r = 0; r < 4; ++r) {
    const int row = 4 * lhi + r;
    const int byte = nxt * 4096 + row * 256 + (((w * 16 + lr) * 2) ^ ((row & 7) << 4));
    *(unsigned short*)(hdbuf + byte) = hs[r];
    store_sc01(xch + wb + row * 128, ((int)(uint32_t)hs[r] << 16) | (t + 1));
  }

  __syncthreads();  // protect this tile's dbuf slots across steps
}

// epilogue y(TT-1) for one tile
template <int HALF, typename XT>
__device__ __forceinline__ void tail_y(
    int mt, int tileSel, const unsigned short* __restrict__ Wot, float bob,
    float* __restrict__ out, int* __restrict__ xch, char* hdbuf,
    int w, int l, int lr, int lhi) {
  short8 ho[4], hq[4];
#pragma unroll
  for (int ko = 0; ko < 4; ++ko) {
    const int byte = 0 * 4096 + lr * 256 + ((ko * 64 + lhi * 16) ^ ((lr & 7) << 4));
    ho[ko] = *(const short8*)(hdbuf + byte);
  }
  const int* pb = xch + ((mt * 2 + (1 - HALF)) * 2 + 0) * 2048 + lr * 128 + 8 * lhi;
  poll_hq(pb, TT, hq);
  if (w == tileSel) {
    const int b0 = mt * 16;
    f32x4 yacc = {bob, bob, bob, bob};
#pragma unroll
    for (int ko = 0; ko < 4; ++ko) {
      short8 wf = *(const short8*)(Wot + (size_t)(HALF * 16 + lr) * 256 + (HALF * 4 + ko) * 32 + 8 * lhi);
      yacc = __builtin_amdgcn_mfma_f32_16x16x32_bf16(ho[ko], wf, yacc, 0, 0, 0);
    }
#pragma unroll
    for (int ko = 0; ko < 4; ++ko) {
      short8 wf = *(const short8*)(Wot + (size_t)(HALF * 16 + lr) * 256 + ((1 - HALF) * 4 + ko) * 32 + 8 * lhi);
      yacc = __builtin_amdgcn_mfma_f32_16x16x32_bf16(hq[ko], wf, yacc, 0, 0, 0);
    }
#pragma unroll
    for (int r = 0; r < 4; ++r)
      out[((size_t)(b0 + 4 * lhi + r) * TT + (TT - 1)) * 32 + HALF * 16 + lr] = yacc[r];
  }
}

// ---- main: 32 blocks x 512 thr; block = (pair p, half h) owns tiles 2p, 2p+1 ------------
// LDS: [0,128K) Wx frags; [128K,136K) tile-A h dbuf; [136K,144K) tile-B h dbuf.
template <int HALF, typename XT>
__device__ __forceinline__ void lstm_pair_core(
    const XT* __restrict__ x, const unsigned short* __restrict__ Wt,
    const unsigned short* __restrict__ Wot, const float* __restrict__ bvec,
    const float* __restrict__ bo, float* __restrict__ out,
    int* __restrict__ xch, int p, char* lds) {
  const int tid = threadIdx.x;
  const int w = tid >> 6, l = tid & 63;
  const int lr = l & 15, lhi = l >> 4;
  const int mtA = 2 * p, mtB = 2 * p + 1;
  const int uloc = HALF * 128 + w * 16 + lr;
  char* hdbufA = lds + 131072;
  char* hdbufB = lds + 139264;

  // stage Wx fragments into LDS (identity map)
#pragma unroll
  for (int g = 0; g < 4; ++g)
#pragma unroll
    for (int kk = 0; kk < 4; ++kk) {
      const unsigned short* wp = Wt + (size_t)(g * 256 + uloc) * 384 + kk * 32 + 8 * lhi;
      *(short8*)(lds + ((size_t)((w * 16 + g * 4 + kk) * 64 + l)) * 16) = *(const short8*)wp;
    }

  short8 Bh[4][8];
#pragma unroll
  for (int g = 0; g < 4; ++g) {
    const unsigned short* wp = Wt + (size_t)(g * 256 + uloc) * 384 + FF + 8 * lhi;
#pragma unroll
    for (int kf = 0; kf < 8; ++kf) Bh[g][kf] = *(const short8*)(wp + kf * 32);
  }
  float bias[4];
#pragma unroll
  for (int g = 0; g < 4; ++g) bias[g] = bvec[g * 256 + uloc];
  const float bob = bo[HALF * 16 + lr];

  float cstA[4] = {0.f, 0.f, 0.f, 0.f}, cstB[4] = {0.f, 0.f, 0.f, 0.f};

  short8 xaA[4], xaB[4];
  {
    const XT* xpA = x + ((size_t)(mtA * 16 + lr) * TT + 0) * FF + 8 * lhi;
    const XT* xpB = x + ((size_t)(mtB * 16 + lr) * TT + 0) * FF + 8 * lhi;
#pragma unroll
    for (int kk = 0; kk < 4; ++kk) { xaA[kk] = load_xfrag(xpA + kk * 32); xaB[kk] = load_xfrag(xpB + kk * 32); }
  }
  __syncthreads();  // Wx staging complete

#pragma unroll 1
  for (int t = 0; t < TT; ++t) {
    step_phase<HALF, XT>(t, mtA, 0, x, Wot, bob, out, xch, lds, hdbufA,
                         Bh, bias, cstA, xaA, w, l, lr, lhi);
    step_phase<HALF, XT>(t, mtB, 1, x, Wot, bob, out, xch, lds, hdbufB,
                         Bh, bias, cstB, xaB, w, l, lr, lhi);
  }
  tail_y<HALF, XT>(mtA, 0, Wot, bob, out, xch, hdbufA, w, l, lr, lhi);
  tail_y<HALF, XT>(mtB, 1, Wot, bob, out, xch, hdbufB, w, l, lr, lhi);
}

template <typename XT>
__global__ void __launch_bounds__(512, 2)
lstm_pair(const XT* __restrict__ x, const unsigned short* __restrict__ Wt,
          const unsigned short* __restrict__ Wot, const float* __restrict__ bvec,
          const float* __restrict__ bo, float* __restrict__ out, int* __restrict__ xch) {
  __shared__ __align__(16) char lds[147456];
  const int bid = blockIdx.x;  // 0..31
  const int p = bid >> 1;
  if ((bid & 1) == 0) lstm_pair_core<0, XT>(x, Wt, Wot, bvec, bo, out, xch, p, lds);
  else                lstm_pair_core<1, XT>(x, Wt, Wot, bvec, bo, out, xch, p, lds);
}

extern "C" void kernel_launch(void* const* d_in, const int* in_sizes, int n_in,
                              void* d_out, int out_size, void* d_ws, size_t ws_size,
                              hipStream_t stream) {
  const float* x  = (const float*)d_in[0];
  const float* Wx = (const float*)d_in[1];
  const float* Wh = (const float*)d_in[2];
  const float* bv = (const float*)d_in[3];
  const float* Wo = (const float*)d_in[4];
  const float* bo = (const float*)d_in[5];

  char* ws = (char*)d_ws;
  size_t off = 0;
  int* xch = (int*)(ws + off);                          off += (size_t)262144 * 4;      // 1 MB
  unsigned short* Wt384 = (unsigned short*)(ws + off);  off += (size_t)1024 * 384 * 2;  // 768 KB
  unsigned short* Wot   = (unsigned short*)(ws + off);  off += (size_t)32 * 256 * 2;
  off = (off + 255) & ~(size_t)255;
  unsigned short* xb = (unsigned short*)(ws + off);
  const size_t need_xb = off + (size_t)BB * TT * FF * 2;  // ~69 MB

  prep_w<<<1153, 384, 0, stream>>>(Wx, Wh, Wo, Wt384, Wot, xch);
  if (ws_size >= need_xb) {
    conv_x<<<32768, 256, 0, stream>>>(x, xb);
    lstm_pair<unsigned short><<<32, 512, 0, stream>>>(xb, Wt384, Wot, bv, bo, (float*)d_out, xch);
  } else {
    lstm_pair<float><<<32, 512, 0, stream>>>(x, Wt384, Wot, bv, bo, (float*)d_out, xch);
  }
}

// Round 14
// 1678.145 us; speedup vs baseline: 5.6467x; 5.6467x over previous
//
#include <hip/hip_runtime.h>
#include <stdint.h>

#define BB 512
#define TT 512
#define FF 128
#define UU 256

typedef float f32x4 __attribute__((ext_vector_type(4)));
typedef short short8 __attribute__((ext_vector_type(8)));
typedef int int4v __attribute__((ext_vector_type(4)));
typedef float float4v __attribute__((ext_vector_type(4)));
typedef unsigned short ushort4v __attribute__((ext_vector_type(4)));

__device__ __forceinline__ unsigned short f2bf(float f) {
  union { float f; uint32_t u; } v; v.f = f;
  uint32_t u = v.u;
  u += 0x7fffu + ((u >> 16) & 1u);
  return (unsigned short)(u >> 16);
}
__device__ __forceinline__ float fast_rcp(float x) { return __builtin_amdgcn_rcpf(x); }
__device__ __forceinline__ float sigmoidf_(float x) { return fast_rcp(1.f + __expf(-x)); }
__device__ __forceinline__ float tanhf_(float x) { return 1.f - 2.f * fast_rcp(1.f + __expf(2.f * x)); }

// ---- prep: W^T combined [1024 cols][384 k] bf16, Wo^T [32][256] bf16, zero xch ---------
__global__ void prep_w(const float* __restrict__ Wx, const float* __restrict__ Wh,
                       const float* __restrict__ Wo,
                       unsigned short* __restrict__ Wt, unsigned short* __restrict__ Wot,
                       int* __restrict__ xch) {
  int bidx = blockIdx.x;
  int tid = threadIdx.x; // 384
  if (bidx < 1024) {
    int n = bidx, k = tid;
    float v = (k < FF) ? Wx[(size_t)k * 1024 + n] : Wh[(size_t)(k - FF) * 1024 + n];
    Wt[(size_t)n * 384 + k] = f2bf(v);
  } else if (bidx == 1024) {
    for (int i = tid; i < 32 * 256; i += 384) {
      int o = i >> 8, u = i & 255;
      Wot[o * 256 + u] = f2bf(Wo[(size_t)u * 32 + o]);
    }
  } else {
    // zero the 1MB tagged-exchange buffer every launch (r10-proven)
    int base = (bidx - 1025) * 2048;  // 128 blocks x 2048 dwords
    for (int i = tid; i < 2048; i += 384) xch[base + i] = 0;
  }
}

// ---- x f32 -> bf16 ----------------------------------------------------------------------
__global__ void conv_x(const float* __restrict__ xf, unsigned short* __restrict__ xb) {
  size_t i = (size_t)blockIdx.x * 1024 + (size_t)threadIdx.x * 4;
  float4v v = *(const float4v*)(xf + i);
  ushort4v o;
  o.x = f2bf(v.x); o.y = f2bf(v.y); o.z = f2bf(v.z); o.w = f2bf(v.w);
  *(ushort4v*)(xb + i) = o;
}

__device__ __forceinline__ short8 load_xfrag(const unsigned short* p) {
  return *(const short8*)p;
}
__device__ __forceinline__ short8 load_xfrag(const float* p) {
  float4v lo = *(const float4v*)p;
  float4v hi = *(const float4v*)(p + 4);
  union { short8 v; unsigned short s[8]; } a;
  a.s[0] = f2bf(lo.x); a.s[1] = f2bf(lo.y); a.s[2] = f2bf(lo.z); a.s[3] = f2bf(lo.w);
  a.s[4] = f2bf(hi.x); a.s[5] = f2bf(hi.y); a.s[6] = f2bf(hi.z); a.s[7] = f2bf(hi.w);
  return a.v;
}

__device__ __forceinline__ void store_sc01(int* p, int v) {
  asm volatile("global_store_dword %0, %1, off sc0 sc1" :: "v"(p), "v"(v) : "memory");
}
__device__ __forceinline__ uint32_t pk2(int lo, int hi) {
  return ((uint32_t)lo >> 16) | ((uint32_t)hi & 0xffff0000u);
}

// ---- recurrent core: r10 champion + speculative poll + y fused in the poll shadow -------
// xch tile (mt, side, slot): [16 rows][128 units] tagged dwords ((bf16<<16)|step);
// tile dword base = ((mt*2 + side)*2 + slot)*2048.
// LDS: [0,128K) Wx frags; [128K,136K) own-h dbuf (2x4K, XOR swz); [136K,140K) partner tile;
//      [140K,148K) Wo frags.
template <int HALF, typename XT>
__device__ __forceinline__ void lstm_core(const XT* __restrict__ x,
                                          const unsigned short* __restrict__ Wt,
                                          const unsigned short* __restrict__ Wot,
                                          const float* __restrict__ bvec,
                                          const float* __restrict__ bo,
                                          float* __restrict__ out,
                                          int* __restrict__ xch, int bid, char* lds) {
  const int mt = bid & 31;
  const int tid = threadIdx.x;
  const int w = tid >> 6, l = tid & 63;
  const int lr = l & 15, lhi = l >> 4;
  const int b0 = mt * 16;
  const int uloc = HALF * 128 + w * 16 + lr;  // global unit col in [0,256)
  char* hlds = lds + 131072;
  char* plds = lds + 139264;
  char* wolds = lds + 143360;

  // stage Wx fragments (this wave's 16) into LDS — identity map
#pragma unroll
  for (int g = 0; g < 4; ++g)
#pragma unroll
    for (int kk = 0; kk < 4; ++kk) {
      const unsigned short* wp = Wt + (size_t)(g * 256 + uloc) * 384 + kk * 32 + 8 * lhi;
      *(short8*)(lds + ((size_t)((w * 16 + g * 4 + kk) * 64 + l)) * 16) = *(const short8*)wp;
    }
  // stage Wo fragments (wave 0): kf 0..7 covers k=0..255, y-cols = HALF*16 + lr
  if (w == 0) {
#pragma unroll
    for (int kf = 0; kf < 8; ++kf) {
      const unsigned short* src = Wot + (size_t)(HALF * 16 + lr) * 256 + kf * 32 + 8 * lhi;
      *(short8*)(wolds + (size_t)(kf * 64 + l) * 16) = *(const short8*)src;
    }
  }

  // Wh fragments in registers: Bh[gate][kf], kf 0..7 over all 256 h-units
  short8 Bh[4][8];
#pragma unroll
  for (int g = 0; g < 4; ++g) {
    const unsigned short* wp = Wt + (size_t)(g * 256 + uloc) * 384 + FF + 8 * lhi;
#pragma unroll
    for (int kf = 0; kf < 8; ++kf) Bh[g][kf] = *(const short8*)(wp + kf * 32);
  }
  float bias[4];
#pragma unroll
  for (int g = 0; g < 4; ++g) bias[g] = bvec[g * 256 + uloc];
  const float bob = bo[HALF * 16 + lr];
  float cst[4] = {0.f, 0.f, 0.f, 0.f};

  constexpr int kf_own = HALF * 4;
  constexpr int kf_par = (1 - HALF) * 4;

  const int rtile = (mt * 2 + (1 - HALF)) * 2;  // + slot
  const int wtile = (mt * 2 + HALF) * 2;

  // redistribute geometry: lane tid polls dwords [4*tid, 4*tid+4) of the partner tile
  const int prow = tid >> 5;
  const int pwbyte = (prow * 256 + (tid & 31) * 8) ^ ((prow & 7) << 4);

  short8 ho[4], hq[4];  // retained h(t) fragments; consumed as h(t-1) in next step's shadow

  // prologue x prefetch (t=0)
  short8 xa[4];
  {
    const XT* xp = x + ((size_t)(b0 + lr) * TT + 0) * FF + 8 * lhi;
#pragma unroll
    for (int kk = 0; kk < 4; ++kk) xa[kk] = load_xfrag(xp + kk * 32);
  }
  __syncthreads();  // staging complete

#pragma unroll 1
  for (int t = 0; t < TT; ++t) {
    const int cur = t & 1, nxt = cur ^ 1;
    const int* pp = xch + (rtile + cur) * 2048 + 4 * tid;

    // (a) speculative tagged poll issue — no waitcnt; lands while we compute below
    int4v a;
    if (t > 0) {
      asm volatile("global_load_dwordx4 %0, %1, off sc0 sc1"
                   : "=&v"(a) : "v"(pp) : "memory");
    }

    // (b) y[t-2] = h(t-1)·Wo + bo in the shadow (wave 0; consumes retained ho/hq)
    if (t >= 2 && w == 0) {
      f32x4 yacc = {bob, bob, bob, bob};
#pragma unroll
      for (int ko = 0; ko < 4; ++ko) {
        short8 wf = *(const short8*)(wolds + (size_t)((kf_own + ko) * 64 + l) * 16);
        yacc = __builtin_amdgcn_mfma_f32_16x16x32_bf16(ho[ko], wf, yacc, 0, 0, 0);
      }
#pragma unroll
      for (int ko = 0; ko < 4; ++ko) {
        short8 wf = *(const short8*)(wolds + (size_t)((kf_par + ko) * 64 + l) * 16);
        yacc = __builtin_amdgcn_mfma_f32_16x16x32_bf16(hq[ko], wf, yacc, 0, 0, 0);
      }
#pragma unroll
      for (int r = 0; r < 4; ++r)
        out[((size_t)(b0 + 4 * lhi + r) * TT + (t - 2)) * 32 + HALF * 16 + lr] = yacc[r];
    }

    f32x4 acc[4];
#pragma unroll
    for (int g = 0; g < 4; ++g) { f32x4 a4 = {bias[g], bias[g], bias[g], bias[g]}; acc[g] = a4; }

    // (c) own-half h(t) from LDS dbuf (overwrites retained ho)
    if (t > 0) {
#pragma unroll
      for (int ko = 0; ko < 4; ++ko) {
        const int byte = cur * 4096 + lr * 256 + ((ko * 64 + lhi * 16) ^ ((lr & 7) << 4));
        ho[ko] = *(const short8*)(hlds + byte);
      }
#pragma unroll
      for (int ko = 0; ko < 4; ++ko)
#pragma unroll
        for (int g = 0; g < 4; ++g)
          acc[g] = __builtin_amdgcn_mfma_f32_16x16x32_bf16(ho[ko], Bh[g][kf_own + ko], acc[g], 0, 0, 0);
    }

    // (d) x-part: B-frags streamed from LDS Wx
#pragma unroll
    for (int kk = 0; kk < 4; ++kk) {
      short8 bx[4];
#pragma unroll
      for (int g = 0; g < 4; ++g)
        bx[g] = *(const short8*)(lds + ((size_t)((w * 16 + g * 4 + kk) * 64 + l)) * 16);
#pragma unroll
      for (int g = 0; g < 4; ++g)
        acc[g] = __builtin_amdgcn_mfma_f32_16x16x32_bf16(xa[kk], bx[g], acc[g], 0, 0, 0);
    }

    // (e) x prefetch for t+1
    {
      const int tn = (t + 1 < TT) ? t + 1 : t;
      const XT* xp = x + ((size_t)(b0 + lr) * TT + tn) * FF + 8 * lhi;
#pragma unroll
      for (int kk = 0; kk < 4; ++kk) xa[kk] = load_xfrag(xp + kk * 32);
    }

    if (t > 0) {
      // (f) check speculative load; spin on miss (16B/lane)
      asm volatile("s_waitcnt vmcnt(0)" ::: "memory");
      __builtin_amdgcn_sched_barrier(0);  // rule #18: no consumer motion above the wait
      while (!__all(((((a.x ^ t) | (a.y ^ t)) | ((a.z ^ t) | (a.w ^ t))) & 0xffff) == 0)) {
        asm volatile("global_load_dwordx4 %0, %1, off sc0 sc1\n\ts_waitcnt vmcnt(0)"
                     : "=&v"(a) : "v"(pp) : "memory");
      }
      __builtin_amdgcn_sched_barrier(0);

      // (g) redistribute through LDS (strip tags), read A-frags, partner MFMAs
      uint32_t d0 = pk2(a.x, a.y), d1 = pk2(a.z, a.w);
      *(uint64_t*)(plds + pwbyte) = ((uint64_t)d1 << 32) | d0;
      __syncthreads();  // barrier A: partner tile complete
#pragma unroll
      for (int ko = 0; ko < 4; ++ko) {
        const int byte = (lr * 256 + lhi * 16 + ko * 64) ^ ((lr & 7) << 4);
        hq[ko] = *(const short8*)(plds + byte);
      }
#pragma unroll
      for (int ko = 0; ko < 4; ++ko)
#pragma unroll
        for (int g = 0; g < 4; ++g)
          acc[g] = __builtin_amdgcn_mfma_f32_16x16x32_bf16(hq[ko], Bh[g][kf_par + ko], acc[g], 0, 0, 0);
    }

    // (h) gates
    unsigned short hs[4];
#pragma unroll
    for (int r = 0; r < 4; ++r) {
      float zi = acc[0][r], zf = acc[1][r], zg = acc[2][r], zo = acc[3][r];
      float si = sigmoidf_(zi), sf = sigmoidf_(zf), so = sigmoidf_(zo);
      float tg = tanhf_(zg);
      float cn = sf * cst[r] + si * tg;
      cst[r] = cn;
      hs[r] = f2bf(so * tanhf_(cn));
    }

    // (i) publish h(t+1): tagged xch stores FIRST (visibility clock), then LDS dbuf
    const int wb = (wtile + nxt) * 2048 + w * 16 + lr;
#pragma unroll
    for (int r = 0; r < 4; ++r)
      store_sc01(xch + wb + (4 * lhi + r) * 128, ((int)(uint32_t)hs[r] << 16) | (t + 1));
#pragma unroll
    for (int r = 0; r < 4; ++r) {
      const int row = 4 * lhi + r;
      const int byte = nxt * 4096 + row * 256 + (((w * 16 + lr) * 2) ^ ((row & 7) << 4));
      *(unsigned short*)(hlds + byte) = hs[r];
    }

    __syncthreads();  // barrier B: protect LDS dbuf + partner tile across steps
  }

  // ---- epilogue: y[TT-2] from retained h(TT-1); y[TT-1] from h(TT) ----------------------
  if (w == 0) {
    f32x4 yacc = {bob, bob, bob, bob};
#pragma unroll
    for (int ko = 0; ko < 4; ++ko) {
      short8 wf = *(const short8*)(wolds + (size_t)((kf_own + ko) * 64 + l) * 16);
      yacc = __builtin_amdgcn_mfma_f32_16x16x32_bf16(ho[ko], wf, yacc, 0, 0, 0);
    }
#pragma unroll
    for (int ko = 0; ko < 4; ++ko) {
      short8 wf = *(const short8*)(wolds + (size_t)((kf_par + ko) * 64 + l) * 16);
      yacc = __builtin_amdgcn_mfma_f32_16x16x32_bf16(hq[ko], wf, yacc, 0, 0, 0);
    }
#pragma unroll
    for (int r = 0; r < 4; ++r)
      out[((size_t)(b0 + 4 * lhi + r) * TT + (TT - 2)) * 32 + HALF * 16 + lr] = yacc[r];
  }
  {
    // h(TT): own half from LDS slot 0; partner via poll tag TT (slot 0)
    const int* pp = xch + (rtile + 0) * 2048 + 4 * tid;
    int4v a;
    do {
      asm volatile("global_load_dwordx4 %0, %1, off sc0 sc1\n\ts_waitcnt vmcnt(0)"
                   : "=&v"(a) : "v"(pp) : "memory");
    } while (!__all(((((a.x ^ TT) | (a.y ^ TT)) | ((a.z ^ TT) | (a.w ^ TT))) & 0xffff) == 0));
    __builtin_amdgcn_sched_barrier(0);
    uint32_t d0 = pk2(a.x, a.y), d1 = pk2(a.z, a.w);
    *(uint64_t*)(plds + pwbyte) = ((uint64_t)d1 << 32) | d0;
    __syncthreads();
    if (w == 0) {
      f32x4 yacc = {bob, bob, bob, bob};
#pragma unroll
      for (int ko = 0; ko < 4; ++ko) {
        const int byte = 0 * 4096 + lr * 256 + ((ko * 64 + lhi * 16) ^ ((lr & 7) << 4));
        short8 hof = *(const short8*)(hlds + byte);
        short8 wf = *(const short8*)(wolds + (size_t)((kf_own + ko) * 64 + l) * 16);
        yacc = __builtin_amdgcn_mfma_f32_16x16x32_bf16(hof, wf, yacc, 0, 0, 0);
      }
#pragma unroll
      for (int ko = 0; ko < 4; ++ko) {
        const int byte = (lr * 256 + lhi * 16 + ko * 64) ^ ((lr & 7) << 4);
        short8 hqf = *(const short8*)(plds + byte);
        short8 wf = *(const short8*)(wolds + (size_t)((kf_par + ko) * 64 + l) * 16);
        yacc = __builtin_amdgcn_mfma_f32_16x16x32_bf16(hqf, wf, yacc, 0, 0, 0);
      }
#pragma unroll
      for (int r = 0; r < 4; ++r)
        out[((size_t)(b0 + 4 * lhi + r) * TT + (TT - 1)) * 32 + HALF * 16 + lr] = yacc[r];
    }
  }
}

template <typename XT>
__global__ void __launch_bounds__(512, 2)
lstm_main14(const XT* __restrict__ x, const unsigned short* __restrict__ Wt,
            const unsigned short* __restrict__ Wot, const float* __restrict__ bvec,
            const float* __restrict__ bo, float* __restrict__ out, int* __restrict__ xch) {
  __shared__ __align__(16) char lds[151552];  // 128K Wx + 8K dbuf + 4K partner + 8K Wo
  const int bid = blockIdx.x;
  if (bid < 32) lstm_core<0, XT>(x, Wt, Wot, bvec, bo, out, xch, bid, lds);
  else          lstm_core<1, XT>(x, Wt, Wot, bvec, bo, out, xch, bid, lds);
}

extern "C" void kernel_launch(void* const* d_in, const int* in_sizes, int n_in,
                              void* d_out, int out_size, void* d_ws, size_t ws_size,
                              hipStream_t stream) {
  const float* x  = (const float*)d_in[0];
  const float* Wx = (const float*)d_in[1];
  const float* Wh = (const float*)d_in[2];
  const float* bv = (const float*)d_in[3];
  const float* Wo = (const float*)d_in[4];
  const float* bo = (const float*)d_in[5];

  char* ws = (char*)d_ws;
  size_t off = 0;
  int* xch = (int*)(ws + off);                          off += (size_t)262144 * 4;      // 1 MB
  unsigned short* Wt384 = (unsigned short*)(ws + off);  off += (size_t)1024 * 384 * 2;  // 768 KB
  unsigned short* Wot   = (unsigned short*)(ws + off);  off += (size_t)32 * 256 * 2;
  off = (off + 255) & ~(size_t)255;
  unsigned short* xb = (unsigned short*)(ws + off);
  const size_t need_xb = off + (size_t)BB * TT * FF * 2;  // ~69 MB

  prep_w<<<1153, 384, 0, stream>>>(Wx, Wh, Wo, Wt384, Wot, xch);
  if (ws_size >= need_xb) {
    conv_x<<<32768, 256, 0, stream>>>(x, xb);
    lstm_main14<unsigned short><<<64, 512, 0, stream>>>(xb, Wt384, Wot, bv, bo, (float*)d_out, xch);
  } else {
    lstm_main14<float><<<64, 512, 0, stream>>>(x, Wt384, Wot, bv, bo, (float*)d_out, xch);
  }
}